// Round 1
// baseline (1173.688 us; speedup 1.0000x reference)
//
#include <hip/hip_runtime.h>
#include <hip/hip_bf16.h>
#include <math.h>

#define L_TOK 1569
#define DM 192
#define DI 384
#define DS 16
#define DTR 12
#define DCONV 4
#define XDBL_N (DTR + 2*DS)   // 44
#define DEPTH 8
#define NCHUNK 25
#define CLEN 64

// ---------------------------------------------------------------------------
// Patch embedding: one block per token. Block 0 writes cls+pos; others gather
// the 3x16x16 patch into LDS and dot with patch_w rows.
// ---------------------------------------------------------------------------
__global__ __launch_bounds__(256) void patch_embed_kernel(
    const float* __restrict__ x, const float* __restrict__ pw,
    const float* __restrict__ pb, const float* __restrict__ cls,
    const float* __restrict__ pos, float* __restrict__ tok) {
  int bx = blockIdx.x;
  if (bx == 0) {
    if (threadIdx.x < DM) tok[threadIdx.x] = cls[threadIdx.x] + pos[threadIdx.x];
    return;
  }
  __shared__ float px[768];
  int patch = bx - 1;
  int t = patch / 196;
  int r = patch % 196;
  int h = r / 14;
  int w = r % 14;
  for (int k = threadIdx.x; k < 768; k += 256) {
    int c = k >> 8, p = (k >> 4) & 15, q = k & 15;
    px[k] = x[((size_t)(c*8 + t)*224 + h*16 + p)*224 + w*16 + q];
  }
  __syncthreads();
  int e = threadIdx.x;
  if (e < DM) {
    const float* pwr = pw + (size_t)e*768;
    float acc = pb[e];
#pragma unroll 8
    for (int k = 0; k < 768; ++k) acc = fmaf(px[k], pwr[k], acc);
    tok[(size_t)bx*DM + e] = acc + pos[(size_t)bx*DM + e];
  }
}

// ---------------------------------------------------------------------------
// LayerNorm over 192 features. One wave (64 threads) per token, 3 elems/lane.
// ---------------------------------------------------------------------------
__global__ __launch_bounds__(64) void ln_kernel(
    const float* __restrict__ in, float* __restrict__ out,
    const float* __restrict__ g, const float* __restrict__ b) {
  int tokn = blockIdx.x;
  int lane = threadIdx.x;
  const float* row = in + (size_t)tokn*DM;
  float x0 = row[lane], x1 = row[lane+64], x2 = row[lane+128];
  float s = x0 + x1 + x2;
  float s2 = x0*x0 + x1*x1 + x2*x2;
#pragma unroll
  for (int off = 1; off < 64; off <<= 1) {
    s  += __shfl_xor(s,  off, 64);
    s2 += __shfl_xor(s2, off, 64);
  }
  float m = s * (1.0f/192.0f);
  float v = s2 * (1.0f/192.0f) - m*m;
  float rs = rsqrtf(v + 1e-5f);
  float* orow = out + (size_t)tokn*DM;
  orow[lane]     = (x0 - m)*rs*g[lane]     + b[lane];
  orow[lane+64]  = (x1 - m)*rs*g[lane+64]  + b[lane+64];
  orow[lane+128] = (x2 - m)*rs*g[lane+128] + b[lane+128];
}

// ---------------------------------------------------------------------------
// Generic fp32 GEMM: C[M,N] = A[M,K] * B[N,K]^T (+bias) with epilogue.
// epi: 0 = none, 1 = softplus(v + bias), 2 = C += v (residual accumulate)
// BM=BN=64, BK=16, 256 threads, 4x4 micro-tile.
// ---------------------------------------------------------------------------
__global__ __launch_bounds__(256) void gemm_kernel(
    const float* __restrict__ A, int lda,
    const float* __restrict__ B, int ldb,
    float* __restrict__ C, int ldc,
    int M, int N, int K,
    const float* __restrict__ bias, int epi) {
  __shared__ float As[16][68];
  __shared__ float Bs[16][68];
  int tid = threadIdx.x;
  int m0 = blockIdx.y * 64, n0 = blockIdx.x * 64;
  int lr = tid >> 2;          // 0..63
  int lk = (tid & 3) * 4;     // 0,4,8,12
  int trow = tid >> 4;        // 0..15
  int tcol = tid & 15;        // 0..15
  float acc[4][4] = {};

  for (int k0 = 0; k0 < K; k0 += 16) {
    bool fullk = (k0 + 16 <= K);
    // stage A -> As[k][m]
    {
      int m = m0 + lr;
      float v[4] = {0.f, 0.f, 0.f, 0.f};
      if (m < M) {
        const float* ap = A + (size_t)m*lda + k0 + lk;
        if (fullk) {
          float4 t4 = *(const float4*)ap;
          v[0] = t4.x; v[1] = t4.y; v[2] = t4.z; v[3] = t4.w;
        } else {
#pragma unroll
          for (int j = 0; j < 4; ++j) if (k0 + lk + j < K) v[j] = ap[j];
        }
      }
#pragma unroll
      for (int j = 0; j < 4; ++j) As[lk+j][lr] = v[j];
    }
    // stage B -> Bs[k][n]
    {
      int n = n0 + lr;
      float v[4] = {0.f, 0.f, 0.f, 0.f};
      if (n < N) {
        const float* bp = B + (size_t)n*ldb + k0 + lk;
        if (fullk) {
          float4 t4 = *(const float4*)bp;
          v[0] = t4.x; v[1] = t4.y; v[2] = t4.z; v[3] = t4.w;
        } else {
#pragma unroll
          for (int j = 0; j < 4; ++j) if (k0 + lk + j < K) v[j] = bp[j];
        }
      }
#pragma unroll
      for (int j = 0; j < 4; ++j) Bs[lk+j][lr] = v[j];
    }
    __syncthreads();
#pragma unroll
    for (int kk = 0; kk < 16; ++kk) {
      float4 a = *(const float4*)&As[kk][trow*4];
      float4 b = *(const float4*)&Bs[kk][tcol*4];
      float av[4] = {a.x, a.y, a.z, a.w};
      float bv[4] = {b.x, b.y, b.z, b.w};
#pragma unroll
      for (int i = 0; i < 4; ++i)
#pragma unroll
        for (int j = 0; j < 4; ++j)
          acc[i][j] = fmaf(av[i], bv[j], acc[i][j]);
    }
    __syncthreads();
  }

#pragma unroll
  for (int i = 0; i < 4; ++i) {
    int m = m0 + trow*4 + i;
    if (m >= M) continue;
#pragma unroll
    for (int j = 0; j < 4; ++j) {
      int n = n0 + tcol*4 + j;
      if (n >= N) continue;
      float v = acc[i][j];
      if (bias) v += bias[n];
      if (epi == 1) v = (v > 20.0f) ? v : log1pf(expf(v));
      float* cp = C + (size_t)m*ldc + n;
      if (epi == 2) v += *cp;
      *cp = v;
    }
  }
}

// ---------------------------------------------------------------------------
// Causal depthwise conv (4 taps) + SiLU. u lives in xz[:, 0:384].
// ---------------------------------------------------------------------------
__global__ __launch_bounds__(256) void conv_silu_kernel(
    const float* __restrict__ xz, const float* __restrict__ Wc,
    const float* __restrict__ bc, float* __restrict__ uc) {
  int idx = blockIdx.x * 256 + threadIdx.x;
  if (idx >= L_TOK * DI) return;
  int t = idx / DI, c = idx % DI;
  float acc = bc[c];
#pragma unroll
  for (int k = 0; k < DCONV; ++k) {
    int tt = t - (DCONV - 1) + k;
    if (tt >= 0) acc = fmaf(xz[(size_t)tt*2*DI + c], Wc[c*DCONV + k], acc);
  }
  uc[idx] = acc / (1.0f + expf(-acc));
}

// ---------------------------------------------------------------------------
// Selective scan, phase 1: per-chunk local scan from zero state.
// grid.x = 24 d-groups (16 d each), grid.y = 25 chunks. 256 thr = 16d x 16n.
// ---------------------------------------------------------------------------
__global__ __launch_bounds__(256) void scan_p1(
    const float* __restrict__ delta, const float* __restrict__ uc,
    const float* __restrict__ xdbl, const float* __restrict__ A_log,
    float* __restrict__ cP, float* __restrict__ cS) {
  __shared__ float ds[CLEN][16], us[CLEN][16], bs[CLEN][16];
  int dl = threadIdx.x >> 4, n = threadIdx.x & 15;
  int d0 = blockIdx.x * 16;
  int t0 = blockIdx.y * CLEN;
  int nt = min(CLEN, L_TOK - t0);
  for (int i = threadIdx.x; i < CLEN*16; i += 256) {
    int tt = i >> 4, dd = i & 15;
    if (tt < nt) {
      int t = t0 + tt;
      ds[tt][dd] = delta[(size_t)t*DI + d0 + dd];
      us[tt][dd] = uc[(size_t)t*DI + d0 + dd];
      bs[tt][dd] = xdbl[(size_t)t*XDBL_N + DTR + dd];
    }
  }
  __syncthreads();
  int d = d0 + dl;
  float a2 = -expf(A_log[d*DS + n]) * 1.44269504088896340736f;
  float s = 0.0f, P = 1.0f;
  for (int tt = 0; tt < nt; ++tt) {
    float dlt = ds[tt][dl], uu = us[tt][dl], Bv = bs[tt][n];
    float dA = exp2f(dlt * a2);
    s = fmaf(dA, s, dlt * Bv * uu);
    P *= dA;
  }
  int o = (blockIdx.y * DI + d) * DS + n;
  cP[o] = P;
  cS[o] = s;
}

// ---------------------------------------------------------------------------
// Phase 2: chunk-carry scan. 6144 independent (d,n) recurrences over 25 chunks.
// ---------------------------------------------------------------------------
__global__ __launch_bounds__(256) void scan_p2(
    const float* __restrict__ cP, const float* __restrict__ cS,
    float* __restrict__ cIn) {
  int idx = blockIdx.x * 256 + threadIdx.x;  // 0..6143
  float in = 0.0f;
  for (int c = 0; c < NCHUNK; ++c) {
    int o = c * (DI*DS) + idx;
    cIn[o] = in;
    in = fmaf(cP[o], in, cS[o]);
  }
}

// ---------------------------------------------------------------------------
// Phase 3: re-scan with carry-in, emit y fused with u*Dp and silu(z) gate.
// ---------------------------------------------------------------------------
__global__ __launch_bounds__(256) void scan_p3(
    const float* __restrict__ delta, const float* __restrict__ uc,
    const float* __restrict__ xdbl, const float* __restrict__ xz,
    const float* __restrict__ A_log, const float* __restrict__ Dp,
    const float* __restrict__ cIn, float* __restrict__ yy) {
  __shared__ float ds[CLEN][16], us[CLEN][16], bs[CLEN][16], cs[CLEN][16], zs[CLEN][16];
  int dl = threadIdx.x >> 4, n = threadIdx.x & 15;
  int d0 = blockIdx.x * 16;
  int t0 = blockIdx.y * CLEN;
  int nt = min(CLEN, L_TOK - t0);
  for (int i = threadIdx.x; i < CLEN*16; i += 256) {
    int tt = i >> 4, dd = i & 15;
    if (tt < nt) {
      int t = t0 + tt;
      ds[tt][dd] = delta[(size_t)t*DI + d0 + dd];
      us[tt][dd] = uc[(size_t)t*DI + d0 + dd];
      bs[tt][dd] = xdbl[(size_t)t*XDBL_N + DTR + dd];
      cs[tt][dd] = xdbl[(size_t)t*XDBL_N + DTR + DS + dd];
      zs[tt][dd] = xz[(size_t)t*2*DI + DI + d0 + dd];
    }
  }
  __syncthreads();
  int d = d0 + dl;
  float a2 = -expf(A_log[d*DS + n]) * 1.44269504088896340736f;
  float s = cIn[(blockIdx.y * DI + d) * DS + n];
  float dpv = Dp[d];
  for (int tt = 0; tt < nt; ++tt) {
    float dlt = ds[tt][dl], uu = us[tt][dl], Bv = bs[tt][n];
    float dA = exp2f(dlt * a2);
    s = fmaf(dA, s, dlt * Bv * uu);
    float p = s * cs[tt][n];
    p += __shfl_xor(p, 1, 64);
    p += __shfl_xor(p, 2, 64);
    p += __shfl_xor(p, 4, 64);
    p += __shfl_xor(p, 8, 64);
    if (n == 0) {
      float z = zs[tt][dl];
      float y = fmaf(uu, dpv, p);
      y *= z / (1.0f + expf(-z));
      yy[(size_t)(t0 + tt)*DI + d] = y;
    }
  }
}

// ---------------------------------------------------------------------------
extern "C" void kernel_launch(void* const* d_in, const int* in_sizes, int n_in,
                              void* d_out, int out_size, void* d_ws, size_t ws_size,
                              hipStream_t stream) {
  const float* x       = (const float*)d_in[0];
  const float* patch_w = (const float*)d_in[1];
  const float* patch_b = (const float*)d_in[2];
  const float* cls_tok = (const float*)d_in[3];
  const float* pos_emb = (const float*)d_in[4];
  const float* ln_g    = (const float*)d_in[5];
  const float* ln_b    = (const float*)d_in[6];
  const float* W_in    = (const float*)d_in[7];
  const float* Wc      = (const float*)d_in[8];
  const float* bc      = (const float*)d_in[9];
  const float* Wx      = (const float*)d_in[10];
  const float* W_dt    = (const float*)d_in[11];
  const float* b_dt    = (const float*)d_in[12];
  const float* A_log   = (const float*)d_in[13];
  const float* Dp      = (const float*)d_in[14];
  const float* W_out   = (const float*)d_in[15];
  const float* fn_g    = (const float*)d_in[16];
  const float* fn_b    = (const float*)d_in[17];

  float* ws = (float*)d_ws;
  float* cur   = ws;                       // 1569*192
  float* h     = cur   + L_TOK*DM;         // 1569*192
  float* xz    = h     + L_TOK*DM;         // 1569*768
  float* uc    = xz    + L_TOK*2*DI;       // 1569*384
  float* xdbl  = uc    + L_TOK*DI;         // 1569*44
  float* delta = xdbl  + L_TOK*XDBL_N;     // 1569*384
  float* yy    = delta + L_TOK*DI;         // 1569*384
  float* cP    = yy    + L_TOK*DI;         // 25*384*16
  float* cS    = cP    + NCHUNK*DI*DS;
  float* cIn   = cS    + NCHUNK*DI*DS;

  // patch embed + cls + pos
  patch_embed_kernel<<<L_TOK, 256, 0, stream>>>(x, patch_w, patch_b, cls_tok, pos_emb, cur);

  for (int dep = 0; dep < DEPTH; ++dep) {
    const float* g     = ln_g  + dep*DM;
    const float* bb    = ln_b  + dep*DM;
    const float* Win_l = W_in  + (size_t)dep*2*DI*DM;
    const float* Wc_l  = Wc    + (size_t)dep*DI*DCONV;
    const float* bc_l  = bc    + (size_t)dep*DI;
    const float* Wx_l  = Wx    + (size_t)dep*XDBL_N*DI;
    const float* Wdt_l = W_dt  + (size_t)dep*DI*DTR;
    const float* bdt_l = b_dt  + (size_t)dep*DI;
    const float* Alog_l= A_log + (size_t)dep*DI*DS;
    const float* Dp_l  = Dp    + (size_t)dep*DI;
    const float* Wout_l= W_out + (size_t)dep*DM*DI;

    // h = LN(cur)
    ln_kernel<<<L_TOK, 64, 0, stream>>>(cur, h, g, bb);

    // xz = h @ W_in^T : M=1569, N=768, K=192
    {
      dim3 grid((2*DI + 63)/64, (L_TOK + 63)/64);
      gemm_kernel<<<grid, 256, 0, stream>>>(h, DM, Win_l, DM, xz, 2*DI,
                                            L_TOK, 2*DI, DM, nullptr, 0);
    }

    // uc = silu(causal_conv(u))
    conv_silu_kernel<<<(L_TOK*DI + 255)/256, 256, 0, stream>>>(xz, Wc_l, bc_l, uc);

    // xdbl = uc @ Wx^T : M=1569, N=44, K=384
    {
      dim3 grid((XDBL_N + 63)/64, (L_TOK + 63)/64);
      gemm_kernel<<<grid, 256, 0, stream>>>(uc, DI, Wx_l, DI, xdbl, XDBL_N,
                                            L_TOK, XDBL_N, DI, nullptr, 0);
    }

    // delta = softplus(dlt @ W_dt^T + b_dt) : M=1569, N=384, K=12
    {
      dim3 grid((DI + 63)/64, (L_TOK + 63)/64);
      gemm_kernel<<<grid, 256, 0, stream>>>(xdbl, XDBL_N, Wdt_l, DTR, delta, DI,
                                            L_TOK, DI, DTR, bdt_l, 1);
    }

    // selective scan (3-phase chunked)
    {
      dim3 g1(DI/16, NCHUNK);
      scan_p1<<<g1, 256, 0, stream>>>(delta, uc, xdbl, Alog_l, cP, cS);
      scan_p2<<<(DI*DS)/256, 256, 0, stream>>>(cP, cS, cIn);
      scan_p3<<<g1, 256, 0, stream>>>(delta, uc, xdbl, xz, Alog_l, Dp_l, cIn, yy);
    }

    // cur += yy @ W_out^T : M=1569, N=192, K=384
    {
      dim3 grid((DM + 63)/64, (L_TOK + 63)/64);
      gemm_kernel<<<grid, 256, 0, stream>>>(yy, DI, Wout_l, DI, cur, DM,
                                            L_TOK, DM, DI, nullptr, 2);
    }
  }

  // final LN -> d_out
  ln_kernel<<<L_TOK, 64, 0, stream>>>(cur, (float*)d_out, fn_g, fn_b);
}